// Round 10
// baseline (253.896 us; speedup 1.0000x reference)
//
#include <hip/hip_runtime.h>

typedef unsigned short u16;
typedef unsigned int u32;
typedef __attribute__((ext_vector_type(8))) short short8;
typedef __attribute__((ext_vector_type(4))) float f32x4;
typedef __attribute__((ext_vector_type(4))) short short4v;
typedef __attribute__((ext_vector_type(2))) unsigned int uint2v;

#define MFMA_BF16(a, b, c) __builtin_amdgcn_mfma_f32_16x16x32_bf16((a), (b), (c), 0, 0, 0)

__device__ __forceinline__ void gl2lds16(const u16* g, u16* l) {
  __builtin_amdgcn_global_load_lds(
      (const __attribute__((address_space(1))) unsigned int*)g,
      (__attribute__((address_space(3))) unsigned int*)l, 16, 0, 0);
}

__device__ __forceinline__ u16 f2bf(float f) {
  union { float f; unsigned u; } v; v.f = f;
  unsigned r = v.u + 0x7fffu + ((v.u >> 16) & 1u);  // RNE
  return (u16)(r >> 16);
}

// Pack two f32 -> dword of 2x bf16 via NATIVE __bf16 casts (RNE; compiler
// lowers to v_cvt_pk_bf16_f32). Verified R9.
__device__ __forceinline__ u32 pack_bf16(float a, float b) {
  __bf16 ha = (__bf16)a, hb = (__bf16)b;
  u16 ua, ub;
  __builtin_memcpy(&ua, &ha, 2);
  __builtin_memcpy(&ub, &hb, 2);
  return (u32)ua | ((u32)ub << 16);
}

__device__ __forceinline__ void cfence() { asm volatile("" ::: "memory"); }

// exp2 on the trans pipe; arg already in log2 domain.
__device__ __forceinline__ float fast_exp2(float x) {
#if __has_builtin(__builtin_amdgcn_exp2f)
  return __builtin_amdgcn_exp2f(x);
#else
  return __expf(x * 0.6931471805599453f);
#endif
}

// Involution swizzle: XOR bits 4-6 with bits 7-9 (row index at 128B pitch).
// S(S(x))==x, 16B-block preserving. Verified R3/R4/R6 on GEMM, R8 on flash.
// CAUTION (R7 lesson): swz can SET bit 6, so for a second half-offset use
//   swz(pre + 64) == swz(pre) ^ 64   (XOR, never +64 post-swizzle).
__device__ __forceinline__ u32 swz(u32 x) { return x ^ (((x >> 7) & 7u) << 4); }

__global__ void fill_one_f32(float* p, int n) {
  int i = blockIdx.x * blockDim.x + threadIdx.x;
  if (i < n) p[i] = 1.0f;  // ws-too-small sentinel
}

// ---------------------------------------------------------------------------
// Fused prep: [0,2048) downcast x; [2048,5120) transpose w_qkv; rest w_out.
// ---------------------------------------------------------------------------
__global__ void prep_k(const float* __restrict__ x, u16* __restrict__ Xb,
                       const float* __restrict__ w_qkv, u16* __restrict__ wqkvT,
                       const float* __restrict__ w_out, u16* __restrict__ woutT) {
  __shared__ float tile[32][33];
  const int bid = blockIdx.x, t = threadIdx.x;
  if (bid < 2048) {
    const int base = (bid * 256 + t) * 16;
#pragma unroll
    for (int h = 0; h < 2; ++h) {
      const f32x4 v0 = *(const f32x4*)&x[base + h * 8];
      const f32x4 v1 = *(const f32x4*)&x[base + h * 8 + 4];
      short8 o;
      o[0] = (short)f2bf(v0.x); o[1] = (short)f2bf(v0.y);
      o[2] = (short)f2bf(v0.z); o[3] = (short)f2bf(v0.w);
      o[4] = (short)f2bf(v1.x); o[5] = (short)f2bf(v1.y);
      o[6] = (short)f2bf(v1.z); o[7] = (short)f2bf(v1.w);
      *(short8*)&Xb[base + h * 8] = o;
    }
    return;
  }
  const float* src; u16* dst; int R, C, bx, by;
  if (bid < 5120) {
    const int tb = bid - 2048;
    src = w_qkv; dst = wqkvT; R = 1024; C = 3072; bx = tb % 96; by = tb / 96;
  } else {
    const int tb = bid - 5120;
    src = w_out; dst = woutT; R = 1024; C = 1024; bx = tb % 32; by = tb / 32;
  }
  const int tx = t & 31, ty = t >> 5;
  const int r0 = by * 32, c0 = bx * 32;
#pragma unroll
  for (int i = 0; i < 4; ++i)
    tile[ty + i * 8][tx] = src[(size_t)(r0 + ty + i * 8) * C + c0 + tx];
  __syncthreads();
#pragma unroll
  for (int i = 0; i < 4; ++i)
    dst[(size_t)(c0 + ty + i * 8) * R + r0 + tx] = f2bf(tile[tx][ty + i * 8]);
}

// ---------------------------------------------------------------------------
// Pipelined multi-block GEMM  C[M,N] = A[M,K] * Bt[N,K]^T (bf16 k-contig).
// 128x128 tile, BK=32, 256 thr = 4 waves (2x2), wave 64x64 (4x4 frags).
// LDS: 3-slot ring, slot = A 8K + B 8K. Tile packed [64 phys-rows][128 B].
// Staging: global_load_lds linear dest + inverse-swizzled source (rule #21).
// Schedule (R6-verified): STAGE(t+2) -> ds_read(t) -> setprio1 16 MFMA
// setprio0 -> vmcnt(4) -> s_barrier.  Counted vmcnt after MFMA; never 0
// in-loop.  R6: conflicts 0, QKV < 74 us.
// MODE 0: scatter Q/K -> [bh][n][64], V -> V^T [bh][d][2048] (b64-packed).
// MODE 1: fp32 out = C + bias.
// ---------------------------------------------------------------------------
template <int MODE>
__launch_bounds__(256, 2)
__global__ void gemm_bt_k(const u16* __restrict__ A, const u16* __restrict__ Bt,
                          int K, int Ncols,
                          u16* __restrict__ O0, u16* __restrict__ O1,
                          u16* __restrict__ O2,
                          float* __restrict__ Of, const float* __restrict__ biasf) {
  __shared__ __align__(16) u16 Al[3 * 4096];  // 3 x 8 KiB
  __shared__ __align__(16) u16 Bl[3 * 4096];  // 3 x 8 KiB
  const int t = threadIdx.x;
  const int w = t >> 6, l = t & 63;
  const int quad = l >> 4, l16 = l & 15;
  const int m0 = blockIdx.y * 128, n0 = blockIdx.x * 128;
  const int wm = w & 1, wn = w >> 1;

  f32x4 acc[4][4];
#pragma unroll
  for (int a = 0; a < 4; ++a)
#pragma unroll
    for (int b = 0; b < 4; ++b) acc[a][b] = (f32x4){0.f, 0.f, 0.f, 0.f};

  const u32 o0 = (u32)t * 16u, o1 = o0 + 4096u;
  const u32 l0 = swz(o0), l1 = swz(o1 & 8191u);
  const u32 rA0 = (l0 >> 7) * 2 + ((l0 >> 6) & 1), q0 = (l0 >> 4) & 3u;
  const u32 rA1 = (l1 >> 7) * 2 + ((l1 >> 6) & 1), q1 = (l1 >> 4) & 3u;
  const u16* srcA0 = A + (size_t)(m0 + rA0) * K + q0 * 8;
  const u16* srcA1 = A + (size_t)(m0 + rA1) * K + q1 * 8;
  const u16* srcB0 = Bt + (size_t)(n0 + rA0) * K + q0 * 8;
  const u16* srcB1 = Bt + (size_t)(n0 + rA1) * K + q1 * 8;

#define STAGE(kel_, s_)                                      \
  do {                                                       \
    char* _da = (char*)(Al + (s_)*4096);                     \
    char* _db = (char*)(Bl + (s_)*4096);                     \
    gl2lds16(srcA0 + (kel_), (u16*)(_da + o0));              \
    gl2lds16(srcA1 + (kel_), (u16*)(_da + o1));              \
    gl2lds16(srcB0 + (kel_), (u16*)(_db + o0));              \
    gl2lds16(srcB1 + (kel_), (u16*)(_db + o1));              \
  } while (0)

  u32 sa[4], sb[4];
#pragma unroll
  for (int a = 0; a < 4; ++a) {
    const u32 row = wm * 64 + a * 16 + l16;
    sa[a] = swz(((row >> 1) << 7) | ((row & 1) << 6) | ((u32)quad << 4));
  }
#pragma unroll
  for (int b = 0; b < 4; ++b) {
    const u32 row = wn * 64 + b * 16 + l16;
    sb[b] = swz(((row >> 1) << 7) | ((row & 1) << 6) | ((u32)quad << 4));
  }

  const int NT = K >> 5;  // BK=32

  STAGE(0, 0);
  STAGE(32, 1);
  asm volatile("s_waitcnt vmcnt(4)" ::: "memory");
  cfence(); __builtin_amdgcn_s_barrier(); cfence();

  int rd = 0, st = 2;
  int kel = 64;
#pragma unroll 1
  for (int tt = 0; tt < NT - 2; ++tt) {
    STAGE(kel, st);
    kel += 32;
    const char* ca = (const char*)(Al + rd * 4096);
    const char* cb = (const char*)(Bl + rd * 4096);
    short8 av[4], bv[4];
#pragma unroll
    for (int a = 0; a < 4; ++a) av[a] = *(const short8*)(ca + sa[a]);
#pragma unroll
    for (int b = 0; b < 4; ++b) bv[b] = *(const short8*)(cb + sb[b]);
    __builtin_amdgcn_s_setprio(1);
#pragma unroll
    for (int a = 0; a < 4; ++a)
#pragma unroll
      for (int b = 0; b < 4; ++b)
        acc[a][b] = MFMA_BF16(av[a], bv[b], acc[a][b]);
    __builtin_amdgcn_s_setprio(0);
    asm volatile("s_waitcnt vmcnt(4)" ::: "memory");
    cfence(); __builtin_amdgcn_s_barrier(); cfence();
    rd = (rd == 2) ? 0 : rd + 1;
    st = (st == 2) ? 0 : st + 1;
  }
  {
    const char* ca = (const char*)(Al + rd * 4096);
    const char* cb = (const char*)(Bl + rd * 4096);
    short8 av[4], bv[4];
#pragma unroll
    for (int a = 0; a < 4; ++a) av[a] = *(const short8*)(ca + sa[a]);
#pragma unroll
    for (int b = 0; b < 4; ++b) bv[b] = *(const short8*)(cb + sb[b]);
#pragma unroll
    for (int a = 0; a < 4; ++a)
#pragma unroll
      for (int b = 0; b < 4; ++b)
        acc[a][b] = MFMA_BF16(av[a], bv[b], acc[a][b]);
    asm volatile("s_waitcnt vmcnt(0)" ::: "memory");
    cfence(); __builtin_amdgcn_s_barrier(); cfence();
    rd = (rd == 2) ? 0 : rd + 1;
  }
  {
    const char* ca = (const char*)(Al + rd * 4096);
    const char* cb = (const char*)(Bl + rd * 4096);
    short8 av[4], bv[4];
#pragma unroll
    for (int a = 0; a < 4; ++a) av[a] = *(const short8*)(ca + sa[a]);
#pragma unroll
    for (int b = 0; b < 4; ++b) bv[b] = *(const short8*)(cb + sb[b]);
#pragma unroll
    for (int a = 0; a < 4; ++a)
#pragma unroll
      for (int b = 0; b < 4; ++b)
        acc[a][b] = MFMA_BF16(av[a], bv[b], acc[a][b]);
  }
#undef STAGE

#pragma unroll
  for (int a = 0; a < 4; ++a)
#pragma unroll
    for (int b = 0; b < 4; ++b) {
      const int row0 = m0 + wm * 64 + a * 16 + quad * 4;
      const int col = n0 + wn * 64 + b * 16 + l16;
      if (MODE == 0) {
        const int bb = row0 >> 11, n = row0 & 2047;
        const int which = col >> 10, j = col & 1023, h = j >> 6, d = j & 63;
        if (which == 2) {
          short4v o;
#pragma unroll
          for (int r = 0; r < 4; ++r) o[r] = (short)f2bf(acc[a][b][r]);
          *(short4v*)&O2[(((size_t)bb * 16 + h) * 64 + d) * 2048 + n] = o;
        } else {
          u16* dst = which ? O1 : O0;
#pragma unroll
          for (int r = 0; r < 4; ++r)
            dst[(((size_t)bb * 16 + h) * 2048 + (n + r)) * 64 + d] =
                f2bf(acc[a][b][r]);
        }
      } else {
#pragma unroll
        for (int r = 0; r < 4; ++r)
          Of[(size_t)(row0 + r) * Ncols + col] = acc[a][b][r] + biasf[col];
      }
    }
}

// ---------------------------------------------------------------------------
// Causal flash attention v12.  Q,K: [bh][2048][64]; VT: [bh][64][2048] bf16.
// v12: TWO q-tiles per block (qi = p and 7-p), ONE merged k-loop.
// Grid 256 = 4 p-groups x 64 bh (flat%8 = bh%8 -> XCD-local K/V).
// Every block does exactly (4p+4)+(4(7-p)+4) = 36 tile-computes -> equal
// length (R9 lesson: (qi,7-qi) spatial pairs are unequal -> CU half-idle).
// Per k-tile the wave carries TWO independent QK->softmax->PV chains (ILP
// covers the P-LDS roundtrip + softmax latency that TLP couldn't; R8/R9
// nulls showed flash is latency-bound, not conflict- or VALU-bound).
// K/V staged ONCE for both q-tiles (shared bh); barriers ~halved.
// + T5 setprio around MFMA clusters (m191: +4-7% attn).
// Per-tile math byte-identical to R9 (passing): swz'd K/V/P LDS (R8),
// exp2-domain softmax, cvt_pk pack (R9), fixed-max, MFMA ones row-sum,
// diag-only masking, skip-guard subsumes kt<nkt (whi < nkt*64).
// ---------------------------------------------------------------------------
__launch_bounds__(512, 2)
__global__ void flash_k12(const u16* __restrict__ Q, const u16* __restrict__ K,
                          const u16* __restrict__ VT, u16* __restrict__ AO) {
  __shared__ __align__(16) u16 Klds[2][64 * 64];    // [buf][kp][d] 128B pitch
  __shared__ __align__(16) u16 Vt[2][64 * 64];      // [buf][d][kp]
  __shared__ __align__(16) u16 Plds[8][2][16 * 64]; // per-wave, per-ql P
  const int t = threadIdx.x, w = t >> 6, l = t & 63;
  const int quad = l >> 4, l16 = l & 15;
  const int flat = blockIdx.x;
  const int bh = flat & 63;
  const int p = flat >> 6;  // 0..3
  const size_t base = (size_t)bh * 2048 * 64;
  const u16* Qp = Q + base;
  const u16* Kp = K + base;
  const u16* VTp = VT + base;
  const int bb = bh >> 4, hh = bh & 15;
  const float SC2 = 0.18033688011112042f;  // 0.125 * log2(e)
  const float FM2 = -4.328085122666891f;   // -3.0  * log2(e)

  const int qbase[2] = {p * 256, (7 - p) * 256};

  const int kcp = t >> 3;  // staging row (K: kp, VT: d)
  const int kcd = (t & 7) * 8;
  const u32 stoff = swz((u32)(kcp * 128 + (t & 7) * 16));

  short8 ones;
#pragma unroll
  for (int j = 0; j < 8; ++j) ones[j] = (short)0x3F80;

  short8 qf[2][2][2];  // [ql][mi][half]
#pragma unroll
  for (int ql = 0; ql < 2; ++ql)
#pragma unroll
    for (int mi = 0; mi < 2; ++mi) {
      const int qrow = qbase[ql] + w * 32 + mi * 16 + l16;
      qf[ql][mi][0] = *(const short8*)&Qp[(size_t)qrow * 64 + quad * 8];
      qf[ql][mi][1] = *(const short8*)&Qp[(size_t)qrow * 64 + 32 + quad * 8];
    }

  // Swizzled frag-read offsets. Second half via ^64 (R7 lesson).
  u32 koff0[4], koff1[4];
#pragma unroll
  for (int nf = 0; nf < 4; ++nf) {
    const u32 pre = (u32)((nf * 16 + l16) * 128 + quad * 16);
    koff0[nf] = swz(pre);
    koff1[nf] = koff0[nf] ^ 64u;
  }
  u32 pwoff[4];
#pragma unroll
  for (int nf = 0; nf < 4; ++nf)
    pwoff[nf] = swz((u32)(l16 * 128 + nf * 32 + quad * 8));
  const u32 proff0 = swz((u32)(l16 * 128 + quad * 16));
  const u32 proff1 = proff0 ^ 64u;

  f32x4 oacc[2][2][4], lacc[2][2];
#pragma unroll
  for (int ql = 0; ql < 2; ++ql)
#pragma unroll
    for (int mi = 0; mi < 2; ++mi) {
      lacc[ql][mi] = (f32x4){0.f, 0.f, 0.f, 0.f};
#pragma unroll
      for (int df = 0; df < 4; ++df)
        oacc[ql][mi][df] = (f32x4){0.f, 0.f, 0.f, 0.f};
    }

  const int nktMax = 4 * (7 - p) + 4;  // q-tile 1 dominates (7-p > p)
  const int wlo[2] = {qbase[0] + w * 32, qbase[1] + w * 32};
  const int whi[2] = {wlo[0] + 31, wlo[1] + 31};

  short8 kv = *(const short8*)&Kp[(size_t)kcp * 64 + kcd];
  short8 vv = *(const short8*)&VTp[(size_t)kcp * 2048 + kcd];

#pragma unroll 1
  for (int kt = 0; kt < nktMax; ++kt) {
    const int buf = kt & 1;
    *(short8*)((char*)Klds[buf] + stoff) = kv;
    *(short8*)((char*)Vt[buf] + stoff) = vv;
    __syncthreads();

    if (kt + 1 < nktMax) {
      kv = *(const short8*)&Kp[(size_t)((kt + 1) * 64 + kcp) * 64 + kcd];
      vv = *(const short8*)&VTp[(size_t)kcp * 2048 + (kt + 1) * 64 + kcd];
    }

#pragma unroll
    for (int ql = 0; ql < 2; ++ql) {
      const bool skip = (kt * 64 > whi[ql]);  // wave-uniform; subsumes kt<nkt
      if (!skip) {
        // ---- S^T = K Q : A = K-frag (m=kp), B = Q regs (n=qrow)
        f32x4 sa[2][4];
        __builtin_amdgcn_s_setprio(1);
#pragma unroll
        for (int nf = 0; nf < 4; ++nf) {
          const char* kb = (const char*)Klds[buf];
          const short8 kf0 = *(const short8*)(kb + koff0[nf]);
          const short8 kf1 = *(const short8*)(kb + koff1[nf]);
#pragma unroll
          for (int mi = 0; mi < 2; ++mi) {
            f32x4 s = (f32x4){0.f, 0.f, 0.f, 0.f};
            s = MFMA_BF16(kf0, qf[ql][mi][0], s);
            s = MFMA_BF16(kf1, qf[ql][mi][1], s);
            sa[mi][nf] = s;  // row=kp(quad*4+r within nf), col=qrow(l16)
          }
        }
        __builtin_amdgcn_s_setprio(0);

        const bool needmask = (kt * 64 + 63 > wlo[ql]);  // wave-uniform
        short8 pf[2][2];
#pragma unroll
        for (int mi = 0; mi < 2; ++mi) {
          const int qrow = qbase[ql] + w * 32 + mi * 16 + l16;
          char* pw = (char*)Plds[w][ql];
#pragma unroll
          for (int nf = 0; nf < 4; ++nf) {
            float pe[4];
#pragma unroll
            for (int r = 0; r < 4; ++r) {
              float arg = fmaf(sa[mi][nf][r], SC2, FM2);
              if (needmask) {
                const int kp = kt * 64 + nf * 16 + quad * 4 + r;
                arg = (kp <= qrow) ? arg : -1e9f;
              }
              pe[r] = fast_exp2(arg);
            }
            *(uint2v*)(pw + pwoff[nf]) =
                (uint2v){pack_bf16(pe[0], pe[1]), pack_bf16(pe[2], pe[3])};
          }
          pf[mi][0] = *(const short8*)(pw + proff0);
          pf[mi][1] = *(const short8*)(pw + proff1);
          lacc[ql][mi] = MFMA_BF16(pf[mi][0], ones, lacc[ql][mi]);
          lacc[ql][mi] = MFMA_BF16(pf[mi][1], ones, lacc[ql][mi]);
        }

        // ---- O += P V : A = pf (m=qrow), B = V^T rows (n=d, k=kp)
        __builtin_amdgcn_s_setprio(1);
#pragma unroll
        for (int df = 0; df < 4; ++df) {
          const char* vb = (const char*)Vt[buf];
          const short8 vf0 = *(const short8*)(vb + koff0[df]);
          const short8 vf1 = *(const short8*)(vb + koff1[df]);
#pragma unroll
          for (int mi = 0; mi < 2; ++mi) {
            oacc[ql][mi][df] = MFMA_BF16(pf[mi][0], vf0, oacc[ql][mi][df]);
            oacc[ql][mi][df] = MFMA_BF16(pf[mi][1], vf1, oacc[ql][mi][df]);
          }
        }
        __builtin_amdgcn_s_setprio(0);
      }
    }
  }

  // ---- epilogue: AO[b][n][hh*64+d] = O / l   (both q-tiles)
#pragma unroll
  for (int ql = 0; ql < 2; ++ql)
#pragma unroll
    for (int mi = 0; mi < 2; ++mi) {
      const int srow = qbase[ql] + w * 32 + mi * 16 + quad * 4;
#pragma unroll
      for (int df = 0; df < 4; ++df)
#pragma unroll
        for (int r = 0; r < 4; ++r) {
          const int n = srow + r;
          const int d = df * 16 + l16;
          AO[((size_t)bb * 2048 + n) * 1024 + hh * 64 + d] =
              f2bf(oacc[ql][mi][df][r] / lacc[ql][mi][r]);
        }
    }
}

// ---------------------------------------------------------------------------
extern "C" void kernel_launch(void* const* d_in, const int* in_sizes, int n_in,
                              void* d_out, int out_size, void* d_ws, size_t ws_size,
                              hipStream_t stream) {
  const float* x = (const float*)d_in[0];      // [4,2048,1024] fp32
  const float* w_qkv = (const float*)d_in[1];  // [1024,3072] fp32
  const float* w_out = (const float*)d_in[2];  // [1024,1024] fp32
  const float* b_out = (const float*)d_in[3];  // [1024] fp32
  float* out = (float*)d_out;                  // [4,2048,1024] fp32

  const size_t MB = 1024 * 1024;
  if (ws_size < 72 * MB) {
    fill_one_f32<<<(out_size + 255) / 256, 256, 0, stream>>>(out, out_size);
    return;
  }

  char* ws = (char*)d_ws;
  u16* wqkvT = (u16*)(ws);             // [3072][1024] bf16   6 MB
  u16* woutT = (u16*)(ws + 6 * MB);    // [1024][1024] bf16   2 MB
  u16* Xb = (u16*)(ws + 8 * MB);       // [8192][1024] bf16  16 MB
  u16* AO = Xb;                        // aliases Xb (dead after QKV GEMM)
  u16* Qb = (u16*)(ws + 24 * MB);      // [64][2048][64]     16 MB
  u16* Kb = (u16*)(ws + 40 * MB);      // 16 MB
  u16* VbT = (u16*)(ws + 56 * MB);     // [64][64][2048]     16 MB (end 72 MB)

  prep_k<<<6144, 256, 0, stream>>>(x, Xb, w_qkv, wqkvT, w_out, woutT);
  gemm_bt_k<0><<<dim3(3072 / 128, 8192 / 128), 256, 0, stream>>>(
      Xb, wqkvT, 1024, 3072, Qb, Kb, VbT, nullptr, nullptr);
  flash_k12<<<256, 512, 0, stream>>>(Qb, Kb, VbT, AO);
  gemm_bt_k<1><<<dim3(1024 / 128, 8192 / 128), 256, 0, stream>>>(
      AO, woutT, 1024, 1024, nullptr, nullptr, nullptr, out, b_out);
}